// Round 15
// baseline (394.222 us; speedup 1.0000x reference)
//
#include <hip/hip_runtime.h>
#include <cstdint>
#include <cstddef>

// SelfAttention: B=8, S=2048, D=512, fp32 in/out.
// R11 (fourth submit; broker timeouts, never ran): occupancy AND intensity.
// R10 lesson: 16x16 MFMA (both ops from LDS) halves FLOP/LDS-byte -> traffic
// doubled -> regression. R11: 32 Q-rows, KT=64, 4 waves = (kh key-half,
// s k-half), 32x32x16 MFMA, Q-frags in REGISTERS (qf[16], loaded once;
// phase A reads only K: 16 reads/wave/kt). k-halves combined via
// conflict-free LDS exchange (stride-72B, s1 write / s0 sum). LDS 79.9KB ->
// 2 blocks/CU, barrier-decoupled phase overlap. vf issued BEFORE K(kt+1) so
// phase-C vmcnt wait leaves K prefetch in flight.
// ws: [qh 16M][kh 16M][vh 16M][vt 16M (xh aliases)][Wt 1.5M] = 65.5 MiB.

#define SEQ 2048
#define DIM 512
#define NB 8
#define BSZ (NB * SEQ)
#define KT 64
#define NT (SEQ / KT)
#define QROWS 32

typedef __attribute__((ext_vector_type(8))) _Float16 half8;
typedef __attribute__((ext_vector_type(4))) _Float16 half4;
typedef __attribute__((ext_vector_type(2))) __fp16 fp16x2;
typedef __attribute__((ext_vector_type(4))) float f32x4;
typedef __attribute__((ext_vector_type(16))) float f32x16;

__device__ __forceinline__ unsigned short f2h(float f) {
  _Float16 h = (_Float16)f;
  return __builtin_bit_cast(unsigned short, h);
}
__device__ __forceinline__ half8 ld_frag(const unsigned short* p) {
  return *(const half8*)(const void*)p;
}
__device__ __forceinline__ void gl_lds16(const unsigned short* g, unsigned short* l) {
  __builtin_amdgcn_global_load_lds(
      (__attribute__((address_space(1))) void*)g,
      (__attribute__((address_space(3))) void*)l, 16, 0, 0);
}
// Fused waitcnt+barrier (single asm block: nothing schedules between them).
__device__ __forceinline__ void bar_vm0() {
  asm volatile("s_waitcnt vmcnt(0)\ns_barrier" ::: "memory");
}
__device__ __forceinline__ void bar_lgkm() {
  asm volatile("s_waitcnt lgkmcnt(0)\ns_barrier" ::: "memory");
}
__device__ __forceinline__ void bar_lgkm_vm0() {
  asm volatile("s_waitcnt lgkmcnt(0) vmcnt(0)\ns_barrier" ::: "memory");
}

// ---------------------------------------------------------------------------
__global__ __launch_bounds__(256) void cvt_x_kernel(
    const float* __restrict__ X, unsigned short* __restrict__ xh)
{
  size_t i0 = ((size_t)blockIdx.x * 256 + threadIdx.x) * 8;
  float4 a = *(const float4*)&X[i0];
  float4 b = *(const float4*)&X[i0 + 4];
  ushort4 o0; o0.x = f2h(a.x); o0.y = f2h(a.y); o0.z = f2h(a.z); o0.w = f2h(a.w);
  ushort4 o1; o1.x = f2h(b.x); o1.y = f2h(b.y); o1.z = f2h(b.z); o1.w = f2h(b.w);
  *(ushort4*)&xh[i0] = o0;
  *(ushort4*)&xh[i0 + 4] = o1;
}

// ---------------------------------------------------------------------------
__global__ __launch_bounds__(256) void cvt_w_kernel(
    const float* __restrict__ Wq, const float* __restrict__ Wk,
    const float* __restrict__ Wv, unsigned short* __restrict__ Wt)
{
  const int z = blockIdx.z;
  const float* W = (z == 0) ? Wq : (z == 1) ? Wk : Wv;
  unsigned short* out = Wt + (size_t)z * DIM * DIM;
  const int k0 = blockIdx.x * 64, n0 = blockIdx.y * 64;
  const int t = threadIdx.x;
  __shared__ unsigned short tl[64 * 72];
#pragma unroll
  for (int i = 0; i < 4; i++) {
    int f = t + 256 * i;
    int kr = f >> 4, c4 = (f & 15) * 4;
    float4 v = *(const float4*)&W[(size_t)(k0 + kr) * DIM + n0 + c4];
    tl[(c4 + 0) * 72 + kr] = f2h(v.x);
    tl[(c4 + 1) * 72 + kr] = f2h(v.y);
    tl[(c4 + 2) * 72 + kr] = f2h(v.z);
    tl[(c4 + 3) * 72 + kr] = f2h(v.w);
  }
  __syncthreads();
#pragma unroll
  for (int i = 0; i < 2; i++) {
    int f = t + 256 * i;
    int nr = f >> 3, k8 = (f & 7) * 8;
    *(uint4*)&out[(size_t)(n0 + nr) * DIM + k0 + k8] = *(const uint4*)&tl[nr * 72 + k8];
  }
}

// ---------------------------------------------------------------------------
// proj (unchanged): qkv[z] = fp16(xh @ Wt[z]^T + b[z]).
// ---------------------------------------------------------------------------
__global__ __launch_bounds__(256) void proj_kernel(
    const unsigned short* __restrict__ xh, const unsigned short* __restrict__ Wt,
    const float* __restrict__ bq, const float* __restrict__ bk,
    const float* __restrict__ bv, unsigned short* __restrict__ outbase)
{
  const int z = blockIdx.z;
  const unsigned short* Wz = Wt + (size_t)z * DIM * DIM;
  const float* bias = (z == 0) ? bq : (z == 1) ? bk : bv;
  unsigned short* out = outbase + (size_t)z * BSZ * DIM;
  const int m0 = blockIdx.x * 128, n0 = blockIdx.y * 128;
  const int t = threadIdx.x, lane = t & 63, wave = t >> 6;
  const int wrow = (wave >> 1) * 64, wcol = (wave & 1) * 64;
  const int lr = lane & 15, lq = (lane >> 4) * 8;

  __shared__ unsigned short sm[128 * 132];
  unsigned short* As = sm;
  unsigned short* Bs = sm + 128 * 64;

  f32x4 acc[4][4];
  const f32x4 zero = {0.f, 0.f, 0.f, 0.f};
#pragma unroll
  for (int r = 0; r < 4; r++)
#pragma unroll
    for (int c = 0; c < 4; c++) acc[r][c] = zero;

  for (int k0 = 0; k0 < DIM; k0 += 64) {
    __syncthreads();
#pragma unroll
    for (int i = 0; i < 4; i++) {
      int f = t + 256 * i;
      int row = f >> 3, c8 = (f & 7) * 8;
      gl_lds16(&xh[(size_t)(m0 + row) * DIM + k0 + c8], &As[i * 2048 + wave * 512]);
      gl_lds16(&Wz[(size_t)(n0 + row) * DIM + k0 + c8], &Bs[i * 2048 + wave * 512]);
    }
    __syncthreads();
#pragma unroll
    for (int kk = 0; kk < 64; kk += 32) {
      half8 a[4], b[4];
#pragma unroll
      for (int r = 0; r < 4; r++) a[r] = ld_frag(&As[(wrow + 16 * r + lr) * 64 + kk + lq]);
#pragma unroll
      for (int c = 0; c < 4; c++) b[c] = ld_frag(&Bs[(wcol + 16 * c + lr) * 64 + kk + lq]);
#pragma unroll
      for (int r = 0; r < 4; r++)
#pragma unroll
        for (int c = 0; c < 4; c++)
          acc[r][c] = __builtin_amdgcn_mfma_f32_16x16x32_f16(a[r], b[c], acc[r][c], 0, 0, 0);
    }
  }
  __syncthreads();
#pragma unroll
  for (int c = 0; c < 4; c++) {
    float bb = bias[n0 + wcol + 16 * c + lr];
#pragma unroll
    for (int r = 0; r < 4; r++)
#pragma unroll
      for (int e = 0; e < 4; e++)
        sm[(wrow + 16 * r + (lane >> 4) * 4 + e) * 132 + wcol + 16 * c + lr] =
            f2h(acc[r][c][e] + bb);
  }
  __syncthreads();
#pragma unroll
  for (int i = 0; i < 8; i++) {
    int f = t + 256 * i;
    int row = f >> 4, c8 = (f & 15) * 8;
    *(uint4*)&out[(size_t)(m0 + row) * DIM + n0 + c8] = *(const uint4*)&sm[row * 132 + c8];
  }
}

// ---------------------------------------------------------------------------
__global__ __launch_bounds__(256) void vtrans_kernel(
    const unsigned short* __restrict__ vh, unsigned short* __restrict__ vt)
{
  const int b = blockIdx.z;
  const int s0 = blockIdx.x * 64, n0 = blockIdx.y * 64;
  const int t = threadIdx.x;
  __shared__ unsigned short tl[64 * 72];
#pragma unroll
  for (int i = 0; i < 2; i++) {
    int f = t + 256 * i;
    int sr = f >> 3, c8 = (f & 7) * 8;
    uint4 raw = *(const uint4*)&vh[((size_t)b * SEQ + s0 + sr) * DIM + n0 + c8];
    unsigned short u[8];
    *(uint4*)u = raw;
#pragma unroll
    for (int j = 0; j < 8; j++) tl[(c8 + j) * 72 + sr] = u[j];
  }
  __syncthreads();
#pragma unroll
  for (int i = 0; i < 2; i++) {
    int f = t + 256 * i;
    int nr = f >> 3, s8 = (f & 7) * 8;
    *(uint4*)&vt[((size_t)b * DIM + n0 + nr) * SEQ + s0 + s8] = *(const uint4*)&tl[nr * 72 + s8];
  }
}

// ---------------------------------------------------------------------------
// flash R11. Block = 32 Q rows, 4 waves: (kh = wave&1, s = wave>>1).
// Wave computes S^T tile [keys kh*32..+32][qrows 0..32] over k-half s*256.
// Per kt:
//   top bar_vm0 (K(kt) landed) -> issue vfA (dc0..3)
//   -> A: 2x8 chained mfma_32x32x16, A=K from LDS, B=Q from REGS (qf[16])
//   -> s1: write partial sacc to xbuf (stride-72B float2, conflict-free)
//   -> bar#1 -> issue vfB THEN K(kt+1) (same Kbuf; A-reads drained)
//   -> s0: sum partner partial; row max (in-lane 16 + xor32); mpart[kh]
//   -> bar#2 -> s0: defer-max, alpha/abuf/fbuf, P b64 writes, lpart
//   -> bar#3 -> lrun (w0), uniform-skip rescale (all), pf reads
//   -> C: 32x mfma_16x16x32 (rg2 x dc8 x kslot2), V from regs.
// LDS 79.9 KB -> 2 blocks/CU (barrier-decoupled overlap). Grid 512.
// ---------------------------------------------------------------------------
#define PSTR 68   // Pbuf row stride (halves): b64 P-writes conflict-free
#define OSTR 516  // Obuf row stride (floats)
#define XSTR 18   // xbuf lane stride (dwords) = 72B: b64 exchange conflict-free

__global__ __launch_bounds__(256, 2) void flash_kernel(
    const unsigned short* __restrict__ Qb, const unsigned short* __restrict__ Kb,
    const unsigned short* __restrict__ Vtb, float* __restrict__ Ob)
{
  const int zb = blockIdx.x & 7;              // batch -> XCD affinity
  const int q0 = (blockIdx.x >> 3) * QROWS;   // q-tile base row
  const unsigned short* Q = Qb + (size_t)zb * SEQ * DIM;
  const unsigned short* K = Kb + (size_t)zb * SEQ * DIM;
  const unsigned short* V = Vtb + (size_t)zb * DIM * SEQ;  // [d][s]
  float* Out = Ob + (size_t)zb * SEQ * DIM;

  const int t = threadIdx.x, lane = t & 63, wave = t >> 6;
  const int l31 = lane & 31, hi = lane >> 5;
  const int kh = wave & 1, sh = wave >> 1;    // key-half, k-half
  const int lr = lane & 15, lq4 = lane >> 4;
  const float L2E = 1.4426950408889634f;

  // LDS carve (halves): Kbuf 32768 | Pbuf 32*68=2176 | xbuf 4608 (2 x 64 x
  // 18 dwords) | mpart 128 | lpart 128 | abuf 64 | lrun 64 | fbuf 8
  // = 39944 halves = 79888 B  -> 2 blocks/CU.
  __shared__ unsigned short lds[39944];
  unsigned short* Kbuf = lds;                 // [64 keys][512], swizzled
  unsigned short* Pbuf = lds + 32768;         // [32 qrows][PSTR]
  float* xbuf = (float*)(lds + 34944);        // [2 kh][64 lanes][XSTR]
  float* mpart = (float*)(lds + 39552);       // [2 kh][32 rows]
  float* lpart = mpart + 64;                  // [2 kh][32 rows]
  float* abuf  = lpart + 64;                  // [32 rows]
  float* lrun  = abuf + 32;                   // [32 rows]
  unsigned int* fbuf = (unsigned int*)(lrun + 32);  // [4] keep flags

  if (t < 32) lrun[t] = 0.f;

  // staging offsets (swizzled chunk ^= row&7). koff[i&7] + (i>>3)*32*DIM
  // covers 64 K rows; Q (32 rows) uses koff[0..7] directly.
  int koff[8];
#pragma unroll
  for (int i = 0; i < 8; i++) {
    int f = t + 256 * i;
    int row = f >> 6, c = f & 63;
    koff[i] = row * DIM + (c ^ (row & 7)) * 8;
  }

  // ---- stage Q -> Kbuf (temp), read qf (Q B-frags, k-half sh), swap to K(0) ----
#pragma unroll
  for (int i = 0; i < 8; i++)
    gl_lds16(&Q[(size_t)q0 * DIM + koff[i]], &Kbuf[i * 2048 + wave * 512]);
  bar_lgkm_vm0();
  half8 qf[16];
  {
    const int qrow = l31, qsw = qrow & 7;
#pragma unroll
    for (int j = 0; j < 16; j++)
      qf[j] = ld_frag(&Kbuf[qrow * 512 + (((32 * sh + 2 * j + hi) ^ qsw) << 3)]);
  }
  __syncthreads();  // all qf reads done before K(0) overwrites
#pragma unroll
  for (int i = 0; i < 16; i++)
    gl_lds16(&K[koff[i & 7] + (i >> 3) * 32 * DIM], &Kbuf[i * 2048 + wave * 512]);

  // ---- running state ----
  f32x4 acc[16];  // [rg 0..1][dc 0..7]: row rg*16+lq4*4+e, d wave*128+dc*16+lr
  const f32x4 zero = {0.f, 0.f, 0.f, 0.f};
#pragma unroll
  for (int ob = 0; ob < 16; ob++) acc[ob] = zero;
  float m_run = -__builtin_inff();  // per lane (s0 waves): qrow l31

  const int keyrow = kh * 32 + l31, ksw = keyrow & 7;
  const unsigned short* Kc = Kbuf + keyrow * 512;
  float* xme = &xbuf[(size_t)kh * 64 * XSTR + lane * XSTR];

  for (int kt = 0; kt < NT; kt++) {
    bar_vm0();  // K(kt) landed for all waves

    // ---- vfA: wave's d 0..63 of its 128-d slice (covered by phase A) ----
    const unsigned short* Vb = V + (size_t)(wave * 128 + lr) * SEQ + kt * KT + lq4 * 8;
    half8 vfA[8];
#pragma unroll
    for (int dc = 0; dc < 4; dc++)
#pragma unroll
      for (int ks = 0; ks < 2; ks++)
        vfA[dc * 2 + ks] = ld_frag(Vb + (size_t)dc * 16 * SEQ + ks * 32);

    // ===== phase A: S^T partial = K·Q^T over k-half sh (2 chains of 8) =====
    f32x16 s0c = {0.f, 0.f, 0.f, 0.f, 0.f, 0.f, 0.f, 0.f,
                  0.f, 0.f, 0.f, 0.f, 0.f, 0.f, 0.f, 0.f};
    f32x16 s1c = s0c;
    __builtin_amdgcn_s_setprio(1);
#pragma unroll
    for (int j = 0; j < 8; j++) {
      half8 kf0 = ld_frag(&Kc[((32 * sh + 2 * j + hi) ^ ksw) << 3]);
      half8 kf1 = ld_frag(&Kc[((32 * sh + 2 * (j + 8) + hi) ^ ksw) << 3]);
      s0c = __builtin_amdgcn_mfma_f32_32x32x16_f16(kf0, qf[j], s0c, 0, 0, 0);
      s1c = __builtin_amdgcn_mfma_f32_32x32x16_f16(kf1, qf[j + 8], s1c, 0, 0, 0);
    }
    __builtin_amdgcn_s_setprio(0);
    f32x16 sacc = s0c + s1c;

    // s1 waves: publish partial tile (conflict-free stride-72B float2 writes)
    if (sh == 1) {
#pragma unroll
      for (int q = 0; q < 8; q++) {
        float2 v2; v2.x = sacc[2 * q]; v2.y = sacc[2 * q + 1];
        *(float2*)&xme[2 * q] = v2;
      }
    }
    bar_lgkm();  // #1: xbuf visible; all phase-A Kc reads drained block-wide

    // vfB (d 64..127) FIRST, then K(kt+1): phase-C wait -> vmcnt leaves K alive
    half8 vfB[8];
#pragma unroll
    for (int dc = 0; dc < 4; dc++)
#pragma unroll
      for (int ks = 0; ks < 2; ks++)
        vfB[dc * 2 + ks] = ld_frag(Vb + (size_t)(dc + 4) * 16 * SEQ + ks * 32);
    if (kt + 1 < NT) {
      const unsigned short* Kt = K + (size_t)(kt + 1) * KT * DIM;
#pragma unroll
      for (int i = 0; i < 16; i++)
        gl_lds16(&Kt[koff[i & 7] + (i >> 3) * 32 * DIM], &Kbuf[i * 2048 + wave * 512]);
    }

    // s0 waves: sum partner partial, row-max
    if (sh == 0) {
#pragma unroll
      for (int q = 0; q < 8; q++) {
        float2 v2 = *(const float2*)&xme[2 * q];
        sacc[2 * q] += v2.x;
        sacc[2 * q + 1] += v2.y;
      }
      float mx = sacc[0];
#pragma unroll
      for (int i2 = 1; i2 < 16; i2++) mx = fmaxf(mx, sacc[i2]);
      mx = fmaxf(mx, __shfl_xor(mx, 32, 64));
      if (lane < 32) mpart[kh * 32 + lane] = mx;
    }
    bar_lgkm();  // #2: mpart visible

    if (sh == 0) {
      float mxc = fmaxf(mpart[lane & 31], mpart[32 + (lane & 31)]);
      // defer-max: keep m_run when growth <= 8 (P bounded by e^8 < f16 max)
      bool keep = (mxc - m_run <= 8.0f);
      float mnew = keep ? m_run : mxc;
      float alpha = keep ? 1.0f : exp2f((m_run - mnew) * L2E);
      m_run = mnew;
      if (kh == 0 && lane < 32) abuf[lane] = alpha;
      unsigned long long ball = __ballot(keep);
      if (lane == 0) fbuf[kh] = (ball == ~0ull) ? 1u : 0u;
      // P = exp(S - m): b64 writes, keys contiguous (reg r -> key
      // (r&3)+8*(r>>2)+4*hi), PSTR=68 conflict-free.
      float psum = 0.f;
#pragma unroll
      for (int w2 = 0; w2 < 4; w2++) {
        float p0 = exp2f((sacc[4 * w2 + 0] - mnew) * L2E);
        float p1 = exp2f((sacc[4 * w2 + 1] - mnew) * L2E);
        float p2 = exp2f((sacc[4 * w2 + 2] - mnew) * L2E);
        float p3 = exp2f((sacc[4 * w2 + 3] - mnew) * L2E);
        psum += (p0 + p1) + (p2 + p3);
        fp16x2 pa = __builtin_amdgcn_cvt_pkrtz(p0, p1);
        fp16x2 pb = __builtin_amdgcn_cvt_pkrtz(p2, p3);
        unsigned long long both =
            ((unsigned long long)__builtin_bit_cast(unsigned int, pb) << 32) |
            __builtin_bit_cast(unsigned int, pa);
        *(unsigned long long*)&Pbuf[l31 * PSTR + kh * 32 + w2 * 8 + 4 * hi] = both;
      }
      psum += __shfl_xor(psum, 32, 64);
      if (lane < 32) lpart[kh * 32 + lane] = psum;
    }
    bar_lgkm();  // #3: Pbuf, abuf, lpart, fbuf visible
    if (sh == 0 && kh == 0 && lane < 32) {
      float a = abuf[lane];
      lrun[lane] = a * lrun[lane] + lpart[lane] + lpart[32 + lane];
    }

    // ---- rescale acc only when some row moved its max (block-uniform) ----
    if (!(fbuf[0] & fbuf[1])) {
#pragma unroll
      for (int rg = 0; rg < 2; rg++)
#pragma unroll
        for (int e = 0; e < 4; e++) {
          float a = abuf[rg * 16 + lq4 * 4 + e];
#pragma unroll
          for (int dc = 0; dc < 8; dc++) acc[rg * 8 + dc][e] *= a;
        }
    }

    // ===== phase C: O += P V (wave: all 32 rows x its 128-d slice) =====
    half8 pf[2][2];
#pragma unroll
    for (int rg = 0; rg < 2; rg++)
#pragma unroll
      for (int ks = 0; ks < 2; ks++) {
        const unsigned short* pp = &Pbuf[(rg * 16 + lr) * PSTR + ks * 32 + lq4 * 8];
        half4 lo = *(const half4*)(const void*)pp;
        half4 h2 = *(const half4*)(const void*)(pp + 4);
        half8 v;
#pragma unroll
        for (int q = 0; q < 4; q++) { v[q] = lo[q]; v[4 + q] = h2[q]; }
        pf[rg][ks] = v;
      }
    __builtin_amdgcn_s_setprio(1);
#pragma unroll
    for (int dc = 0; dc < 4; dc++)
#pragma unroll
      for (int rg = 0; rg < 2; rg++) {
        acc[rg * 8 + dc] =
            __builtin_amdgcn_mfma_f32_16x16x32_f16(pf[rg][0], vfA[dc * 2 + 0],
                                                   acc[rg * 8 + dc], 0, 0, 0);
        acc[rg * 8 + dc] =
            __builtin_amdgcn_mfma_f32_16x16x32_f16(pf[rg][1], vfA[dc * 2 + 1],
                                                   acc[rg * 8 + dc], 0, 0, 0);
      }
#pragma unroll
    for (int dc = 4; dc < 8; dc++)
#pragma unroll
      for (int rg = 0; rg < 2; rg++) {
        acc[rg * 8 + dc] =
            __builtin_amdgcn_mfma_f32_16x16x32_f16(pf[rg][0], vfB[(dc - 4) * 2 + 0],
                                                   acc[rg * 8 + dc], 0, 0, 0);
        acc[rg * 8 + dc] =
            __builtin_amdgcn_mfma_f32_16x16x32_f16(pf[rg][1], vfB[(dc - 4) * 2 + 1],
                                                   acc[rg * 8 + dc], 0, 0, 0);
      }
    __builtin_amdgcn_s_setprio(0);
  }

  bar_lgkm_vm0();  // lrun final, all LDS quiesced before Obuf reuse

  // ---- finalize: O /= l, repack via LDS, coalesced stores ----
  float linv[2][4];
#pragma unroll
  for (int rg = 0; rg < 2; rg++)
#pragma unroll
    for (int e = 0; e < 4; e++) linv[rg][e] = 1.0f / lrun[rg * 16 + lq4 * 4 + e];

  float* Obuf = (float*)lds;  // 32 x OSTR x 4B = 66048 B < lrun zone (79744+)
  __syncthreads();
#pragma unroll
  for (int rg = 0; rg < 2; rg++)
#pragma unroll
    for (int e = 0; e < 4; e++) {
      int row = rg * 16 + lq4 * 4 + e;
#pragma unroll
      for (int dc = 0; dc < 8; dc++)
        Obuf[row * OSTR + wave * 128 + dc * 16 + lr] = acc[rg * 8 + dc][e] * linv[rg][e];
    }
  __syncthreads();
#pragma unroll
  for (int i = 0; i < 16; i++) {
    int f = t + 256 * i;
    int row = f >> 7, c4 = (f & 127) * 4;
    *(float4*)&Out[(size_t)(q0 + row) * DIM + c4] = *(const float4*)&Obuf[row * OSTR + c4];
  }
}

// ---------------------------------------------------------------------------
extern "C" void kernel_launch(void* const* d_in, const int* in_sizes, int n_in,
                              void* d_out, int out_size, void* d_ws, size_t ws_size,
                              hipStream_t stream)
{
  const float* X  = (const float*)d_in[0];
  const float* Wq = (const float*)d_in[1];
  const float* bq = (const float*)d_in[2];
  const float* Wk = (const float*)d_in[3];
  const float* bk = (const float*)d_in[4];
  const float* Wv = (const float*)d_in[5];
  const float* bv = (const float*)d_in[6];
  float* Out = (float*)d_out;

  char* ws = (char*)d_ws;
  const size_t MB = 1u << 20;
  unsigned short* qh = (unsigned short*)(ws);            // 16 MiB
  unsigned short* kh = (unsigned short*)(ws + 16 * MB);  // 16 MiB (proj z=1)
  unsigned short* vh = (unsigned short*)(ws + 32 * MB);  // 16 MiB (proj z=2)
  unsigned short* vt = (unsigned short*)(ws + 48 * MB);  // 16 MiB
  unsigned short* xh = (unsigned short*)(ws + 48 * MB);  // alias vt: dead pre-vtrans
  unsigned short* Wt = (unsigned short*)(ws + 64 * MB);  // 1.5 MiB

  cvt_x_kernel<<<dim3(BSZ * DIM / 2048), 256, 0, stream>>>(X, xh);
  cvt_w_kernel<<<dim3(8, 8, 3), 256, 0, stream>>>(Wq, Wk, Wv, Wt);
  proj_kernel<<<dim3(BSZ / 128, DIM / 128, 3), 256, 0, stream>>>(
      xh, Wt, bq, bk, bv, qh);
  vtrans_kernel<<<dim3(SEQ / 64, DIM / 64, NB), 256, 0, stream>>>(vh, vt);
  flash_kernel<<<dim3(NB * SEQ / QROWS), 256, 0, stream>>>(qh, kh, vt, Out);
}